// Round 11
// baseline (108.202 us; speedup 1.0000x reference)
//
#include <hip/hip_runtime.h>
#include <hip/hip_bf16.h>

// MMD loss via bf16 MFMA Gram matrix. R10: scatter-free prep.
// R2-R9 ledger: total - gemm ~= 57-60us across three prep variants; all had
// 16-segment/4KB-stride wave reads (the R6 TA-scatter pattern). New prep:
// every global access >= 1KB contiguous per wave inst.
//
// Zc layout (R7): Zc[ck][row][32], stored quad = q ^ ((row>>1)&3); each mfma
// fragment = one contiguous coalesced 1KB block.
// Lessons: R4 no __threadfence in hot kernel; R5 no forced occupancy (spill);
// R6 no scattered vector loads; R3/R7 barrier-drain plateau.
//
// z = [xf; yf] (8192 x 256). result = (1/4096^2)*(8192*NSIG + sum_{i<j} 2 s_i s_j K_ij)
// ws: [0,4MiB) bf16 Zc; float norms[8192]; float partials[2080].

#define NSIG 5
#define CKS   262144                 // chunk stride in ushorts: 8192 rows * 32
#define NBLK2 2080                   // 64-supergrid triangle: 64*65/2

typedef __attribute__((ext_vector_type(8))) short short8;
typedef __attribute__((ext_vector_type(4))) float floatx4;

// ---- prep v4: block = (s, b, cg, pq). Reads 32 c-row-quarters (1KB contiguous
// per wave inst), LDS-stages bf16, writes contiguous 64B chunk-rows of Zc. ----
__global__ __launch_bounds__(256) void prep_kernel(const float* __restrict__ x,
                                                   const float* __restrict__ y,
                                                   ushort* __restrict__ Zc,
                                                   float* __restrict__ norms) {
    const int bid = blockIdx.x;          // s(1) | b(2) | cg(3) | pq(2)
    const int t = threadIdx.x;
    const int s  = bid >> 7;
    const int b  = (bid >> 5) & 3;
    const int cg = (bid >> 2) & 7;       // K-chunk = 32 c's
    const int pq = bid & 3;              // 256-p quarter
    const float* src = s ? y : x;
    const int p0 = pq << 8;
    const int n0 = (s << 12) + (b << 10) + p0;

    __shared__ ushort tile[32 * 256];    // [c_loc][p] bf16, 16 KB

    // phase 1: 8 iters; each wave inst = 64 lanes x float4 = 1KB contiguous
#pragma unroll
    for (int it = 0; it < 8; ++it) {
        const int g = (it << 8) + t;     // 0..2047
        const int cl = g >> 6;           // c_loc 0..31
        const int pf = (g & 63) << 2;    // p frac 0..252
        const float4 v = *(const float4*)(src +
            ((size_t)((b << 8) + (cg << 5) + cl) << 10) + p0 + pf);
        const __hip_bfloat16 h0 = __float2bfloat16(v.x);
        const __hip_bfloat16 h1 = __float2bfloat16(v.y);
        const __hip_bfloat16 h2 = __float2bfloat16(v.z);
        const __hip_bfloat16 h3 = __float2bfloat16(v.w);
        const uint u0 = (uint)(*(const ushort*)&h0) | ((uint)(*(const ushort*)&h1) << 16);
        const uint u1 = (uint)(*(const ushort*)&h2) | ((uint)(*(const ushort*)&h3) << 16);
        *(uint2*)(&tile[(cl << 8) + pf]) = make_uint2(u0, u1);   // stride 8B: 2-way = free
    }
    __syncthreads();

    // phase 2: thread t = local row r; 32 scalar LDS reads (2 lanes share one
    // dword-bank = free), pack full 64B chunk-row, 4 dwordx4 stores.
    const int r = t;
    const int row = n0 + r;
    const int sw = (row >> 1) & 3;
    float ns = 0.f;
    uint pk[16];
#pragma unroll
    for (int c = 0; c < 32; ++c) {
        const ushort uv = tile[(c << 8) + r];
        const float f = __bfloat162float(*(const __hip_bfloat16*)&uv);
        ns = fmaf(f, f, ns);
        if ((c & 1) == 0) pk[c >> 1] = (uint)uv;
        else              pk[c >> 1] |= ((uint)uv) << 16;
    }
    ushort* dst = Zc + (size_t)cg * CKS + ((size_t)row << 5);
#pragma unroll
    for (int q = 0; q < 4; ++q) {
        const int sq = q ^ sw;
        *(uint4*)(dst + (sq << 3)) = make_uint4(pk[4*q], pk[4*q+1], pk[4*q+2], pk[4*q+3]);
    }
    atomicAdd(&norms[row], ns);          // 8 partial adds per row (one per cg)
}

// ---- GEMM: block = 2x2 wave-tiles (128x128), panel-ordered triangle decode
//      (byte-identical to R9) ----
__global__ __launch_bounds__(256, 3) void gemm_epi(const ushort* __restrict__ Zc,
                                                   const float* __restrict__ norms,
                                                   const float* __restrict__ sigmas,
                                                   float* __restrict__ partials) {
    __shared__ float wsum[4];

    const int t = threadIdx.x;
    const int w = t >> 6, l = t & 63;

    const int lin = blockIdx.x;
    int p = (int)((-4.0f + sqrtf(16.0f + 128.0f * (float)lin)) * (1.0f / 64.0f));
    p = p < 0 ? 0 : (p > 7 ? 7 : p);
    while (p < 7 && 32 * (p + 1) * (p + 1) + 4 * (p + 1) <= lin) ++p;
    while (p > 0 && 32 * p * p + 4 * p > lin) --p;
    const int o = lin - (32 * p * p + 4 * p);
    int c = 7;
#pragma unroll
    for (int cc = 7; cc >= 1; --cc) {
        const int Q = cc * (8 * p + 1) + (cc * (cc - 1)) / 2;
        if (o < Q) c = cc - 1;
    }
    const int Qc = c * (8 * p + 1) + (c * (c - 1)) / 2;
    const int tj2 = 8 * p + c;
    const int ti2 = o - Qc;

    const int ti = (ti2 << 1) + (w >> 1);
    const int tj = (tj2 << 1) + (w & 1);
    const bool active = (ti <= tj);
    const bool diag = (ti == tj);

    const int i0 = ti << 6, j0 = tj << 6;
    const int m = l & 15, q = l >> 4;

    int offA[4], offB[4];
#pragma unroll
    for (int f = 0; f < 4; ++f) {
        const int ra = i0 + (f << 4) + m;
        offA[f] = (ra << 5) + (((q ^ ((ra >> 1) & 3))) << 3);
        const int rb = j0 + (f << 4) + m;
        offB[f] = (rb << 5) + (((q ^ ((rb >> 1) & 3))) << 3);
    }

    floatx4 accf[4][4];
#pragma unroll
    for (int fi = 0; fi < 4; ++fi)
#pragma unroll
        for (int fj = 0; fj < 4; ++fj) accf[fi][fj] = (floatx4){0.f, 0.f, 0.f, 0.f};

    float lsum = 0.f;
    if (active) {
        short8 curA[4], curB[4], nxtA[4], nxtB[4];
#pragma unroll
        for (int f = 0; f < 4; ++f) {
            curA[f] = *(const short8*)(Zc + offA[f]);
            curB[f] = *(const short8*)(Zc + offB[f]);
        }
#pragma unroll
        for (int ck = 0; ck < 8; ++ck) {
            if (ck < 7) {
                const size_t ko = (size_t)(ck + 1) * CKS;
#pragma unroll
                for (int f = 0; f < 4; ++f) {
                    nxtA[f] = *(const short8*)(Zc + ko + offA[f]);
                    nxtB[f] = *(const short8*)(Zc + ko + offB[f]);
                }
            }
#pragma unroll
            for (int fi = 0; fi < 4; ++fi)
#pragma unroll
                for (int fj = 0; fj < 4; ++fj)
                    accf[fi][fj] = __builtin_amdgcn_mfma_f32_16x16x32_bf16(curA[fi], curB[fj], accf[fi][fj], 0, 0, 0);
            if (ck < 7) {
#pragma unroll
                for (int f = 0; f < 4; ++f) { curA[f] = nxtA[f]; curB[f] = nxtB[f]; }
            }
        }

        float c2[NSIG];
#pragma unroll
        for (int k = 0; k < NSIG; ++k) c2[k] = (-0.5f / sigmas[k]) * 1.44269504f;

        const float sgn2 = ((ti < 64) == (tj < 64)) ? 2.f : -2.f;

#pragma unroll
        for (int fi = 0; fi < 4; ++fi) {
            const floatx4 ni4 = *(const floatx4*)(norms + i0 + (fi << 4) + (q << 2));
#pragma unroll
            for (int fj = 0; fj < 4; ++fj) {
                const float njs = norms[j0 + (fj << 4) + m];
#pragma unroll
                for (int v = 0; v < 4; ++v) {
                    float d = fmaf(-2.f, accf[fi][fj][v], ni4[v] + njs);
                    d = fmaxf(d, 0.f);
                    if (diag) {
                        const int dif = ((fi - fj) << 4) + ((q << 2) + v) - m;
                        d = (dif < 0) ? d : 3.0e9f;
                    }
                    accf[fi][fj][v] = d;
                }
            }
        }

        float dmin = accf[0][0][0];
#pragma unroll
        for (int fi = 0; fi < 4; ++fi)
#pragma unroll
            for (int fj = 0; fj < 4; ++fj)
#pragma unroll
                for (int v = 0; v < 4; ++v) dmin = fminf(dmin, accf[fi][fj][v]);
#pragma unroll
        for (int off = 1; off < 64; off <<= 1) dmin = fminf(dmin, __shfl_xor(dmin, off, 64));

#pragma unroll
        for (int k = 0; k < NSIG; ++k) {
            if (c2[k] * dmin >= -126.f) {
#pragma unroll
                for (int fi = 0; fi < 4; ++fi)
#pragma unroll
                    for (int fj = 0; fj < 4; ++fj)
#pragma unroll
                        for (int v = 0; v < 4; ++v)
                            lsum += __builtin_amdgcn_exp2f(c2[k] * accf[fi][fj][v]);
            }
        }
        lsum *= sgn2;
    }

#pragma unroll
    for (int off = 32; off > 0; off >>= 1) lsum += __shfl_down(lsum, off, 64);
    if (l == 0) wsum[w] = lsum;
    __syncthreads();
    if (t == 0) partials[blockIdx.x] = wsum[0] + wsum[1] + wsum[2] + wsum[3];
}

__global__ __launch_bounds__(256) void finalize_kernel(const float* __restrict__ partials,
                                                       float* __restrict__ out) {
    __shared__ double sh[256];
    const int t = threadIdx.x;
    double s = 0.0;
    for (int i = t; i < NBLK2; i += 256) s += (double)partials[i];
    sh[t] = s;
    __syncthreads();
    for (int st = 128; st > 0; st >>= 1) {
        if (t < st) sh[t] += sh[t + st];
        __syncthreads();
    }
    if (t == 0) out[0] = (float)((sh[0] + 8192.0 * NSIG) * (1.0 / (4096.0 * 4096.0)));
}

extern "C" void kernel_launch(void* const* d_in, const int* in_sizes, int n_in,
                              void* d_out, int out_size, void* d_ws, size_t ws_size,
                              hipStream_t stream) {
    const float* x   = (const float*)d_in[0];
    const float* y   = (const float*)d_in[1];
    const float* sig = (const float*)d_in[2];

    ushort* Zc      = (ushort*)d_ws;                                   // 4 MiB
    float* norms    = (float*)((char*)d_ws + (size_t)8192 * 256 * 2);  // 32 KiB
    float* partials = (float*)((char*)norms + 8192 * sizeof(float));   // 2080 floats
    float* out      = (float*)d_out;

    hipMemsetAsync(norms, 0, 8192 * sizeof(float), stream);            // for atomic partials
    prep_kernel<<<256, 256, 0, stream>>>(x, y, Zc, norms);
    gemm_epi<<<NBLK2, 256, 0, stream>>>(Zc, norms, sig, partials);
    finalize_kernel<<<1, 256, 0, stream>>>(partials, out);
}